// Round 1
// baseline (1458.009 us; speedup 1.0000x reference)
//
#include <hip/hip_runtime.h>

#define N_NODES 50000
#define N_EDGES 800000
#define IN_C 512
#define HID_C 256
#define OUT_C 128

// ---------------------------------------------------------------- degree prep
__global__ void init_deg_kernel(float* __restrict__ deg) {
    int i = blockIdx.x * blockDim.x + threadIdx.x;
    if (i < N_NODES) deg[i] = 1.0f;  // self-loop contributes 1
}

__global__ void deg_accum_kernel(const int* __restrict__ ei, float* __restrict__ deg) {
    int e = blockIdx.x * blockDim.x + threadIdx.x;
    if (e < N_EDGES) atomicAdd(&deg[ei[N_EDGES + e]], 1.0f);  // dst row
}

__global__ void dinv_kernel(const float* __restrict__ deg, float* __restrict__ dinv) {
    int i = blockIdx.x * blockDim.x + threadIdx.x;
    if (i < N_NODES) dinv[i] = rsqrtf(deg[i]);  // deg >= 1 always
}

// ---------------------------------------------------------------- fp32 GEMM
// C[M,N] = op(A)[M,K] @ B[K,N]; op = relu if RELU_IN. 64x64 tile, 16 k-slice,
// 256 threads, 4x4 accumulator per thread. N must be divisible by 64, K by 16.
template <bool RELU_IN>
__global__ __launch_bounds__(256) void gemm64_kernel(const float* __restrict__ A,
                                                     const float* __restrict__ B,
                                                     float* __restrict__ C,
                                                     int M, int N, int K) {
    __shared__ float As[16][68];  // [k][m], +4 pad keeps 16B alignment, 2-way banks only
    __shared__ float Bs[16][64];  // [k][n]

    const int tid = threadIdx.x;
    const int tx = tid & 15;   // n-group
    const int ty = tid >> 4;   // m-group
    const int br = blockIdx.y * 64;
    const int bc = blockIdx.x * 64;

    float acc[4][4] = {};

    for (int kk = 0; kk < K; kk += 16) {
        // stage A tile (64 rows x 16 k), transposed into As[k][m]
#pragma unroll
        for (int t = 0; t < 4; t++) {
            int idx = tid + t * 256;
            int r = idx >> 4, c = idx & 15;
            int gr = br + r;
            float v = (gr < M) ? A[(size_t)gr * K + kk + c] : 0.0f;
            if (RELU_IN) v = fmaxf(v, 0.0f);
            As[c][r] = v;
        }
        // stage B tile (16 k x 64 cols)
#pragma unroll
        for (int t = 0; t < 4; t++) {
            int idx = tid + t * 256;
            int r = idx >> 6, c = idx & 63;
            Bs[r][c] = B[(size_t)(kk + r) * N + bc + c];
        }
        __syncthreads();

#pragma unroll
        for (int k = 0; k < 16; k++) {
            float4 a4 = *(const float4*)&As[k][ty * 4];
            float4 b4 = *(const float4*)&Bs[k][tx * 4];
            float ar[4] = {a4.x, a4.y, a4.z, a4.w};
            float bv[4] = {b4.x, b4.y, b4.z, b4.w};
#pragma unroll
            for (int i = 0; i < 4; i++)
#pragma unroll
                for (int j = 0; j < 4; j++) acc[i][j] += ar[i] * bv[j];
        }
        __syncthreads();
    }

#pragma unroll
    for (int i = 0; i < 4; i++) {
        int gr = br + ty * 4 + i;
        if (gr < M) {
            float4 o = make_float4(acc[i][0], acc[i][1], acc[i][2], acc[i][3]);
            *(float4*)&C[(size_t)gr * N + bc + tx * 4] = o;
        }
    }
}

// ------------------------------------------------------- aggregation kernels
// out[i,c] = dinv[i]^2 * H[i,c] + bias[c]   (self-loop term + bias; full init)
__global__ void init_agg_kernel(const float* __restrict__ H, const float* __restrict__ dinv,
                                const float* __restrict__ bias, float* __restrict__ out,
                                int C) {
    size_t idx = (size_t)blockIdx.x * blockDim.x + threadIdx.x;
    if (idx < (size_t)N_NODES * C) {
        int i = (int)(idx / C);
        int c = (int)(idx % C);
        float di = dinv[i];
        out[idx] = di * di * H[idx] + bias[c];
    }
}

// out[dst,c] += dinv[src]*dinv[dst] * H[src,c]   — one block per edge
template <int C>
__global__ void scatter_kernel(const int* __restrict__ ei, const float* __restrict__ H,
                               const float* __restrict__ dinv, float* __restrict__ out) {
    int e = blockIdx.x;
    int c = threadIdx.x;
    int s = ei[e];
    int d = ei[N_EDGES + e];
    float w = dinv[s] * dinv[d];
    atomicAdd(&out[(size_t)d * C + c], w * H[(size_t)s * C + c]);
}

// ---------------------------------------------------------------- launcher
extern "C" void kernel_launch(void* const* d_in, const int* in_sizes, int n_in,
                              void* d_out, int out_size, void* d_ws, size_t ws_size,
                              hipStream_t stream) {
    const float* x  = (const float*)d_in[0];
    const int*   ei = (const int*)d_in[1];
    const float* W1 = (const float*)d_in[2];
    const float* b1 = (const float*)d_in[3];
    const float* W2 = (const float*)d_in[4];
    const float* b2 = (const float*)d_in[5];
    float* out = (float*)d_out;

    // workspace layout (floats)
    float* deg  = (float*)d_ws;                 // 50000 (rounded to 50048)
    float* dinv = deg + 50048;                  // 50000 (rounded to 50048)
    float* H1   = dinv + 50048;                 // 50000*256 = 12.8M
    float* A1   = H1 + (size_t)N_NODES * HID_C; // 50000*256 = 12.8M
    float* H2   = H1;                           // H1 dead after scatter1 -> reuse

    // 1) degrees + rsqrt
    init_deg_kernel<<<(N_NODES + 255) / 256, 256, 0, stream>>>(deg);
    deg_accum_kernel<<<(N_EDGES + 255) / 256, 256, 0, stream>>>(ei, deg);
    dinv_kernel<<<(N_NODES + 255) / 256, 256, 0, stream>>>(deg, dinv);

    // 2) H1 = x @ W1
    {
        dim3 grid(HID_C / 64, (N_NODES + 63) / 64);
        gemm64_kernel<false><<<grid, 256, 0, stream>>>(x, W1, H1, N_NODES, HID_C, IN_C);
    }
    // 3) A1 = aggregate(H1) + b1   (ReLU deferred to GEMM2 load)
    init_agg_kernel<<<(N_NODES * HID_C + 255) / 256, 256, 0, stream>>>(H1, dinv, b1, A1, HID_C);
    scatter_kernel<HID_C><<<N_EDGES, HID_C, 0, stream>>>(ei, H1, dinv, A1);

    // 4) H2 = relu(A1) @ W2
    {
        dim3 grid(OUT_C / 64, (N_NODES + 63) / 64);
        gemm64_kernel<true><<<grid, 256, 0, stream>>>(A1, W2, H2, N_NODES, OUT_C, HID_C);
    }
    // 5) out = aggregate(H2) + b2
    init_agg_kernel<<<(N_NODES * OUT_C + 255) / 256, 256, 0, stream>>>(H2, dinv, b2, out, OUT_C);
    scatter_kernel<OUT_C><<<N_EDGES, OUT_C, 0, stream>>>(ei, H2, dinv, out);
}

// Round 3
// 670.287 us; speedup vs baseline: 2.1752x; 2.1752x over previous
//
#include <hip/hip_runtime.h>
#include <hip/hip_bf16.h>

#define N_NODES 50000
#define N_EDGES 800000
#define IN_C 512
#define HID_C 256
#define OUT_C 128

#define SCAN_BLOCKS 49  // ceil(50000 / 1024)

// ---------------------------------------------------------------- CSR build
__global__ void zero_counts_kernel(int* __restrict__ counts) {
    int i = blockIdx.x * blockDim.x + threadIdx.x;
    if (i < N_NODES) counts[i] = 0;
}

__global__ void count_kernel(const int* __restrict__ ei, int* __restrict__ counts) {
    int e = blockIdx.x * blockDim.x + threadIdx.x;
    if (e < N_EDGES) atomicAdd(&counts[ei[N_EDGES + e]], 1);
}

// Per-block exclusive scan: 256 threads x 4 items = 1024 elems/block.
__global__ __launch_bounds__(256) void scan_part_kernel(const int* __restrict__ counts,
                                                        int* __restrict__ excl,
                                                        int* __restrict__ bsums) {
    __shared__ int tsum[256];
    const int t = threadIdx.x;
    const int base = blockIdx.x * 1024 + t * 4;
    int v[4];
    int s = 0;
#pragma unroll
    for (int j = 0; j < 4; j++) {
        int idx = base + j;
        v[j] = (idx < N_NODES) ? counts[idx] : 0;
        s += v[j];
    }
    tsum[t] = s;
    __syncthreads();
    for (int off = 1; off < 256; off <<= 1) {
        int add = (t >= off) ? tsum[t - off] : 0;
        __syncthreads();
        tsum[t] += add;
        __syncthreads();
    }
    int run = tsum[t] - s;  // exclusive prefix of this thread within block
#pragma unroll
    for (int j = 0; j < 4; j++) {
        int idx = base + j;
        if (idx < N_NODES) excl[idx] = run;
        run += v[j];
    }
    if (t == 255) bsums[blockIdx.x] = tsum[255];
}

__global__ void scan_sums_kernel(int* __restrict__ bsums) {
    if (threadIdx.x == 0) {
        int r = 0;
        for (int i = 0; i < SCAN_BLOCKS; i++) {
            int tmp = bsums[i];
            bsums[i] = r;
            r += tmp;
        }
    }
}

// offsets += block base; copy to cursor; compute dinv; write sentinel.
__global__ void add_dinv_kernel(int* __restrict__ offsets, const int* __restrict__ bsums,
                                int* __restrict__ woff, const int* __restrict__ counts,
                                float* __restrict__ dinv) {
    int i = blockIdx.x * blockDim.x + threadIdx.x;
    if (i < N_NODES) {
        int o = offsets[i] + bsums[i >> 10];
        offsets[i] = o;
        woff[i] = o;
        dinv[i] = rsqrtf(1.0f + (float)counts[i]);
    }
    if (i == 0) offsets[N_NODES] = N_EDGES;
}

__global__ void fill_kernel(const int* __restrict__ ei, int* __restrict__ woff,
                            int* __restrict__ sorted_src) {
    int e = blockIdx.x * blockDim.x + threadIdx.x;
    if (e < N_EDGES) {
        int s = ei[e];
        int d = ei[N_EDGES + e];
        int pos = atomicAdd(&woff[d], 1);
        sorted_src[pos] = s;
    }
}

// ---------------------------------------------------------------- fp32 GEMM
// C[M,N] = op(A)[M,K] @ B[K,N]; op = relu if RELU_IN. Output fp32 or bf16.
// 64x64 tile, 16 k-slice, 256 threads, 4x4 acc/thread. N%64==0, K%16==0.
template <bool RELU_IN, bool BF16_OUT>
__global__ __launch_bounds__(256) void gemm64_kernel(const float* __restrict__ A,
                                                     const float* __restrict__ B,
                                                     void* __restrict__ Cv,
                                                     int M, int N, int K) {
    __shared__ float As[16][68];
    __shared__ float Bs[16][64];

    const int tid = threadIdx.x;
    const int tx = tid & 15;
    const int ty = tid >> 4;
    const int br = blockIdx.y * 64;
    const int bc = blockIdx.x * 64;

    float acc[4][4] = {};

    for (int kk = 0; kk < K; kk += 16) {
#pragma unroll
        for (int t = 0; t < 4; t++) {
            int idx = tid + t * 256;
            int r = idx >> 4, c = idx & 15;
            int gr = br + r;
            float v = (gr < M) ? A[(size_t)gr * K + kk + c] : 0.0f;
            if (RELU_IN) v = fmaxf(v, 0.0f);
            As[c][r] = v;
        }
#pragma unroll
        for (int t = 0; t < 4; t++) {
            int idx = tid + t * 256;
            int r = idx >> 6, c = idx & 63;
            Bs[r][c] = B[(size_t)(kk + r) * N + bc + c];
        }
        __syncthreads();

#pragma unroll
        for (int k = 0; k < 16; k++) {
            float4 a4 = *(const float4*)&As[k][ty * 4];
            float4 b4 = *(const float4*)&Bs[k][tx * 4];
            float ar[4] = {a4.x, a4.y, a4.z, a4.w};
            float bv[4] = {b4.x, b4.y, b4.z, b4.w};
#pragma unroll
            for (int i = 0; i < 4; i++)
#pragma unroll
                for (int j = 0; j < 4; j++) acc[i][j] += ar[i] * bv[j];
        }
        __syncthreads();
    }

#pragma unroll
    for (int i = 0; i < 4; i++) {
        int gr = br + ty * 4 + i;
        if (gr < M) {
            if (BF16_OUT) {
                __hip_bfloat16* C = (__hip_bfloat16*)Cv;
                ushort4 o;
                __hip_bfloat16 h0 = __float2bfloat16(acc[i][0]);
                __hip_bfloat16 h1 = __float2bfloat16(acc[i][1]);
                __hip_bfloat16 h2 = __float2bfloat16(acc[i][2]);
                __hip_bfloat16 h3 = __float2bfloat16(acc[i][3]);
                o.x = *(unsigned short*)&h0;
                o.y = *(unsigned short*)&h1;
                o.z = *(unsigned short*)&h2;
                o.w = *(unsigned short*)&h3;
                *(ushort4*)&C[(size_t)gr * N + bc + tx * 4] = o;
            } else {
                float* C = (float*)Cv;
                float4 o = make_float4(acc[i][0], acc[i][1], acc[i][2], acc[i][3]);
                *(float4*)&C[(size_t)gr * N + bc + tx * 4] = o;
            }
        }
    }
}

// ------------------------------------------------------- gather aggregation
// out[i,c] = dinv[i]^2*H[i,c] + b[c] + sum_{e: dst=i} dinv[i]*dinv[src]*H[src,c]
// One block per node, C threads (thread = channel). No atomics.
template <int C, typename HT>
__global__ void gather_agg_kernel(const int* __restrict__ offsets,
                                  const int* __restrict__ sorted_src,
                                  const HT* __restrict__ H,
                                  const float* __restrict__ dinv,
                                  const float* __restrict__ bias,
                                  float* __restrict__ out) {
    const int i = blockIdx.x;
    const int c = threadIdx.x;
    const float di = dinv[i];
    float acc = di * di * (float)H[(size_t)i * C + c] + bias[c];

    const int k0 = offsets[i];
    const int k1 = offsets[i + 1];
    int k = k0;
    for (; k + 1 < k1; k += 2) {
        int s0 = sorted_src[k];
        int s1 = sorted_src[k + 1];
        float w0 = di * dinv[s0];
        float w1 = di * dinv[s1];
        float h0 = (float)H[(size_t)s0 * C + c];
        float h1 = (float)H[(size_t)s1 * C + c];
        acc += w0 * h0 + w1 * h1;
    }
    if (k < k1) {
        int s0 = sorted_src[k];
        acc += di * dinv[s0] * (float)H[(size_t)s0 * C + c];
    }
    out[(size_t)i * C + c] = acc;
}

// ---------------------------------------------------------------- launcher
extern "C" void kernel_launch(void* const* d_in, const int* in_sizes, int n_in,
                              void* d_out, int out_size, void* d_ws, size_t ws_size,
                              hipStream_t stream) {
    const float* x  = (const float*)d_in[0];
    const int*   ei = (const int*)d_in[1];
    const float* W1 = (const float*)d_in[2];
    const float* b1 = (const float*)d_in[3];
    const float* W2 = (const float*)d_in[4];
    const float* b2 = (const float*)d_in[5];
    float* out = (float*)d_out;

    // workspace layout (4-byte units). Total: 20,200,260 * 4B = 77.1 MiB
    // (known-good R1 layout used 98.0 MiB; R2's 101.5 MiB overflowed ws and
    //  corrupted adjacent allocations -> post-timing divergence. Stay small.)
    int*   counts     = (int*)d_ws;                       // 50048
    int*   offsets    = counts + 50048;                   // 50051 (+sentinel)
    int*   woff       = offsets + 50052;                  // 50048
    int*   bsums      = woff + 50048;                     // 64
    float* dinv       = (float*)(bsums + 64);             // 50048
    int*   sorted_src = (int*)(dinv + 50048);             // 800000
    __hip_bfloat16* H1 = (__hip_bfloat16*)(sorted_src + 800000);  // 12.8M bf16 (25.6 MB)
    float* A1         = (float*)(H1 + (size_t)N_NODES * HID_C);   // 12.8M fp32 (51.2 MB)
    float* H2         = (float*)H1;  // 6.4M fp32 (25.6 MB) — exactly fills H1's region

    // CSR build + norm
    zero_counts_kernel<<<(N_NODES + 255) / 256, 256, 0, stream>>>(counts);
    count_kernel<<<(N_EDGES + 255) / 256, 256, 0, stream>>>(ei, counts);
    scan_part_kernel<<<SCAN_BLOCKS, 256, 0, stream>>>(counts, offsets, bsums);
    scan_sums_kernel<<<1, 64, 0, stream>>>(bsums);
    add_dinv_kernel<<<(N_NODES + 255) / 256, 256, 0, stream>>>(offsets, bsums, woff, counts, dinv);
    fill_kernel<<<(N_EDGES + 255) / 256, 256, 0, stream>>>(ei, woff, sorted_src);

    // layer 1: H1(bf16) = x @ W1
    {
        dim3 grid(HID_C / 64, (N_NODES + 63) / 64);
        gemm64_kernel<false, true><<<grid, 256, 0, stream>>>(x, W1, (void*)H1, N_NODES, HID_C, IN_C);
    }
    gather_agg_kernel<HID_C, __hip_bfloat16><<<N_NODES, HID_C, 0, stream>>>(
        offsets, sorted_src, H1, dinv, b1, A1);

    // layer 2: H2(fp32) = relu(A1) @ W2   (ReLU fused into GEMM A-load)
    {
        dim3 grid(OUT_C / 64, (N_NODES + 63) / 64);
        gemm64_kernel<true, false><<<grid, 256, 0, stream>>>(A1, W2, (void*)H2, N_NODES, OUT_C, HID_C);
    }
    gather_agg_kernel<OUT_C, float><<<N_NODES, OUT_C, 0, stream>>>(
        offsets, sorted_src, H2, dinv, b2, out);
}

// Round 4
// 448.996 us; speedup vs baseline: 3.2473x; 1.4929x over previous
//
#include <hip/hip_runtime.h>
#include <hip/hip_bf16.h>

#define N_NODES 50000
#define N_EDGES 800000
#define IN_C 512
#define HID_C 256
#define OUT_C 128
#define SCAN_BLOCKS 49  // ceil(50000 / 1024)

typedef short bf16x8 __attribute__((ext_vector_type(8)));
typedef float f32x4 __attribute__((ext_vector_type(4)));

__device__ __forceinline__ float bf2f(unsigned short u) {
    return __uint_as_float(((unsigned)u) << 16);
}
__device__ __forceinline__ unsigned short f2bf(float f) {
    __hip_bfloat16 h = __float2bfloat16(f);
    return *(unsigned short*)&h;
}

// ---------------------------------------------------------------- CSR build
__global__ void zero_counts_kernel(int* __restrict__ counts) {
    int i = blockIdx.x * blockDim.x + threadIdx.x;
    if (i < N_NODES) counts[i] = 0;
}

__global__ void count_kernel(const int* __restrict__ ei, int* __restrict__ counts) {
    int e = blockIdx.x * blockDim.x + threadIdx.x;
    if (e < N_EDGES) atomicAdd(&counts[ei[N_EDGES + e]], 1);
}

__global__ __launch_bounds__(256) void scan_part_kernel(const int* __restrict__ counts,
                                                        int* __restrict__ excl,
                                                        int* __restrict__ bsums) {
    __shared__ int tsum[256];
    const int t = threadIdx.x;
    const int base = blockIdx.x * 1024 + t * 4;
    int v[4];
    int s = 0;
#pragma unroll
    for (int j = 0; j < 4; j++) {
        int idx = base + j;
        v[j] = (idx < N_NODES) ? counts[idx] : 0;
        s += v[j];
    }
    tsum[t] = s;
    __syncthreads();
    for (int off = 1; off < 256; off <<= 1) {
        int add = (t >= off) ? tsum[t - off] : 0;
        __syncthreads();
        tsum[t] += add;
        __syncthreads();
    }
    int run = tsum[t] - s;
#pragma unroll
    for (int j = 0; j < 4; j++) {
        int idx = base + j;
        if (idx < N_NODES) excl[idx] = run;
        run += v[j];
    }
    if (t == 255) bsums[blockIdx.x] = tsum[255];
}

__global__ void scan_sums_kernel(int* __restrict__ bsums) {
    if (threadIdx.x == 0) {
        int r = 0;
        for (int i = 0; i < SCAN_BLOCKS; i++) {
            int tmp = bsums[i];
            bsums[i] = r;
            r += tmp;
        }
    }
}

__global__ void add_dinv_kernel(int* __restrict__ offsets, const int* __restrict__ bsums,
                                int* __restrict__ woff, const int* __restrict__ counts,
                                float* __restrict__ dinv) {
    int i = blockIdx.x * blockDim.x + threadIdx.x;
    if (i < N_NODES) {
        int o = offsets[i] + bsums[i >> 10];
        offsets[i] = o;
        woff[i] = o;
        dinv[i] = rsqrtf(1.0f + (float)counts[i]);
    }
    if (i == 0) offsets[N_NODES] = N_EDGES;
}

__global__ void fill_kernel(const int* __restrict__ ei, int* __restrict__ woff,
                            const float* __restrict__ dinv,
                            int* __restrict__ sorted_src, float* __restrict__ sorted_w) {
    int e = blockIdx.x * blockDim.x + threadIdx.x;
    if (e < N_EDGES) {
        int s = ei[e];
        int d = ei[N_EDGES + e];
        int pos = atomicAdd(&woff[d], 1);
        sorted_src[pos] = s;
        sorted_w[pos] = dinv[s];
    }
}

// ---------------------------------------------------------------- casts
__global__ __launch_bounds__(256) void cast_x_kernel(const float* __restrict__ x,
                                                     unsigned short* __restrict__ xb) {
    size_t i = ((size_t)blockIdx.x * 256 + threadIdx.x) * 4;  // grid sized exactly
    float4 v = *(const float4*)&x[i];
    ushort4 o;
    o.x = f2bf(v.x); o.y = f2bf(v.y); o.z = f2bf(v.z); o.w = f2bf(v.w);
    *(ushort4*)&xb[i] = o;
}

// WT[n][k] = bf16(W[k][n]); grid covers N*K exactly
__global__ __launch_bounds__(256) void tcast_kernel(const float* __restrict__ W,
                                                    unsigned short* __restrict__ WT,
                                                    int K, int N) {
    int idx = blockIdx.x * 256 + threadIdx.x;
    int n = idx / K, k = idx - n * K;
    WT[idx] = f2bf(W[(size_t)k * N + n]);
}

// ---------------------------------------------------------------- MFMA GEMM
// C[M,N](bf16) = A[M,K](bf16) @ BT[N,K](bf16)^T. 128x128 block tile, BK=32,
// 256 threads = 4 waves, each wave a 64x64 quadrant via 4x4 of 16x16x32 MFMA.
// global_load_lds width-16 staging (m97 structure). K%32==0, N%128==0.
__global__ __launch_bounds__(256) void mfma_gemm_bt(const unsigned short* __restrict__ A,
                                                    const unsigned short* __restrict__ BT,
                                                    unsigned short* __restrict__ C,
                                                    int M, int N, int K) {
    __shared__ unsigned short As[128 * 32];  // [row][k] 64B rows
    __shared__ unsigned short Bs[128 * 32];

    const int tid = threadIdx.x;
    const int w = tid >> 6;    // wave 0..3
    const int ln = tid & 63;
    const int br = blockIdx.y * 128;
    const int bc = blockIdx.x * 128;

    const int quad = ln >> 4;
    const int l16 = ln & 15;
    const int wr = (w >> 1) * 64;
    const int wc = (w & 1) * 64;

    // staging lane address pieces: chunk = 16 rows x 64B; lane -> row crow, kbyte
    const int crow = ln >> 2;
    const int koff = (ln & 3) * 8;  // elems

    f32x4 acc[4][4];
#pragma unroll
    for (int mt = 0; mt < 4; mt++)
#pragma unroll
        for (int nt = 0; nt < 4; nt++) acc[mt][nt] = (f32x4){0.f, 0.f, 0.f, 0.f};

    for (int kk = 0; kk < K; kk += 32) {
#pragma unroll
        for (int t = 0; t < 2; t++) {
            int c = w + t * 4;
            int row = br + c * 16 + crow;
            row = row < M ? row : M - 1;  // clamp (dup read, stores guarded)
            const unsigned short* gp = A + (size_t)row * K + kk + koff;
            unsigned short* lp = As + c * 512 + ln * 8;
            __builtin_amdgcn_global_load_lds((const __attribute__((address_space(1))) void*)gp,
                                             (__attribute__((address_space(3))) void*)lp,
                                             16, 0, 0);
        }
#pragma unroll
        for (int t = 0; t < 2; t++) {
            int c = w + t * 4;
            int row = bc + c * 16 + crow;  // BT row = C col, always < N
            const unsigned short* gp = BT + (size_t)row * K + kk + koff;
            unsigned short* lp = Bs + c * 512 + ln * 8;
            __builtin_amdgcn_global_load_lds((const __attribute__((address_space(1))) void*)gp,
                                             (__attribute__((address_space(3))) void*)lp,
                                             16, 0, 0);
        }
        __syncthreads();

        bf16x8 af[4], bfr[4];
#pragma unroll
        for (int mt = 0; mt < 4; mt++)
            af[mt] = *(const bf16x8*)&As[(wr + mt * 16 + l16) * 32 + quad * 8];
#pragma unroll
        for (int nt = 0; nt < 4; nt++)
            bfr[nt] = *(const bf16x8*)&Bs[(wc + nt * 16 + l16) * 32 + quad * 8];
#pragma unroll
        for (int mt = 0; mt < 4; mt++)
#pragma unroll
            for (int nt = 0; nt < 4; nt++)
                acc[mt][nt] = __builtin_amdgcn_mfma_f32_16x16x32_bf16(af[mt], bfr[nt],
                                                                      acc[mt][nt], 0, 0, 0);
        __syncthreads();
    }

    // epilogue: D[row=quad*4+r][col=l16] per 16x16 tile
#pragma unroll
    for (int mt = 0; mt < 4; mt++) {
#pragma unroll
        for (int r = 0; r < 4; r++) {
            int gr = br + wr + mt * 16 + quad * 4 + r;
            if (gr < M) {
#pragma unroll
                for (int nt = 0; nt < 4; nt++) {
                    int gc = bc + wc + nt * 16 + l16;
                    C[(size_t)gr * N + gc] = f2bf(acc[mt][nt][r]);
                }
            }
        }
    }
}

// ------------------------------------------------------- gather aggregation
// wave per node; lane handles V=C/64 channels; vector bf16 loads.
// out[i,:] = relu?( dinv[i]^2*H[i,:] + b + sum_e dinv[i]*sorted_w[e]*H[src,:] )
template <int C, bool RELU, bool BF16_OUT>
__global__ __launch_bounds__(256) void gather_agg_kernel(const int* __restrict__ offsets,
                                                         const int* __restrict__ ssrc,
                                                         const float* __restrict__ sw,
                                                         const unsigned short* __restrict__ H,
                                                         const float* __restrict__ dinv,
                                                         const float* __restrict__ bias,
                                                         void* __restrict__ outv) {
    constexpr int V = C / 64;  // 4 (C=256) or 2 (C=128)
    const int node = blockIdx.x * 4 + (threadIdx.x >> 6);
    const int ln = threadIdx.x & 63;
    if (node >= N_NODES) return;
    const int c0 = ln * V;
    const float di = dinv[node];

    float acc[V];
    {  // self term + bias
        const unsigned short* p = H + (size_t)node * C + c0;
        if (V == 4) {
            ushort4 u = *(const ushort4*)p;
            acc[0] = di * di * bf2f(u.x) + bias[c0 + 0];
            acc[1] = di * di * bf2f(u.y) + bias[c0 + 1];
            acc[2] = di * di * bf2f(u.z) + bias[c0 + 2];
            acc[3] = di * di * bf2f(u.w) + bias[c0 + 3];
        } else {
            ushort2 u = *(const ushort2*)p;
            acc[0] = di * di * bf2f(u.x) + bias[c0 + 0];
            acc[1] = di * di * bf2f(u.y) + bias[c0 + 1];
        }
    }

    int k = offsets[node];
    const int k1 = offsets[node + 1];
    for (; k + 1 < k1; k += 2) {
        int s0 = ssrc[k], s1 = ssrc[k + 1];
        float w0 = di * sw[k], w1 = di * sw[k + 1];
        const unsigned short* p0 = H + (size_t)s0 * C + c0;
        const unsigned short* p1 = H + (size_t)s1 * C + c0;
        if (V == 4) {
            ushort4 u0 = *(const ushort4*)p0;
            ushort4 u1 = *(const ushort4*)p1;
            acc[0] += w0 * bf2f(u0.x) + w1 * bf2f(u1.x);
            acc[1] += w0 * bf2f(u0.y) + w1 * bf2f(u1.y);
            acc[2] += w0 * bf2f(u0.z) + w1 * bf2f(u1.z);
            acc[3] += w0 * bf2f(u0.w) + w1 * bf2f(u1.w);
        } else {
            ushort2 u0 = *(const ushort2*)p0;
            ushort2 u1 = *(const ushort2*)p1;
            acc[0] += w0 * bf2f(u0.x) + w1 * bf2f(u1.x);
            acc[1] += w0 * bf2f(u0.y) + w1 * bf2f(u1.y);
        }
    }
    if (k < k1) {
        int s0 = ssrc[k];
        float w0 = di * sw[k];
        const unsigned short* p0 = H + (size_t)s0 * C + c0;
        if (V == 4) {
            ushort4 u0 = *(const ushort4*)p0;
            acc[0] += w0 * bf2f(u0.x);
            acc[1] += w0 * bf2f(u0.y);
            acc[2] += w0 * bf2f(u0.z);
            acc[3] += w0 * bf2f(u0.w);
        } else {
            ushort2 u0 = *(const ushort2*)p0;
            acc[0] += w0 * bf2f(u0.x);
            acc[1] += w0 * bf2f(u0.y);
        }
    }

    if (RELU) {
#pragma unroll
        for (int j = 0; j < V; j++) acc[j] = fmaxf(acc[j], 0.0f);
    }
    if (BF16_OUT) {
        unsigned short* out = (unsigned short*)outv;
        if (V == 4) {
            ushort4 o;
            o.x = f2bf(acc[0]); o.y = f2bf(acc[1]); o.z = f2bf(acc[2]); o.w = f2bf(acc[3]);
            *(ushort4*)&out[(size_t)node * C + c0] = o;
        } else {
            ushort2 o;
            o.x = f2bf(acc[0]); o.y = f2bf(acc[1]);
            *(ushort2*)&out[(size_t)node * C + c0] = o;
        }
    } else {
        float* out = (float*)outv;
        if (V == 4) {
            *(float4*)&out[(size_t)node * C + c0] = make_float4(acc[0], acc[1], acc[2], acc[3]);
        } else {
            *(float2*)&out[(size_t)node * C + c0] = make_float2(acc[0], acc[1]);
        }
    }
}

// ---------------------------------------------------------------- launcher
extern "C" void kernel_launch(void* const* d_in, const int* in_sizes, int n_in,
                              void* d_out, int out_size, void* d_ws, size_t ws_size,
                              hipStream_t stream) {
    const float* x  = (const float*)d_in[0];
    const int*   ei = (const int*)d_in[1];
    const float* W1 = (const float*)d_in[2];
    const float* b1 = (const float*)d_in[3];
    const float* W2 = (const float*)d_in[4];
    const float* b2 = (const float*)d_in[5];
    float* out = (float*)d_out;

    // workspace layout (4-byte words). Total 21,082,180 words = 84.3 MiB
    // (< known-good 98 MiB; R2's 101.5 MiB overflowed and corrupted inputs).
    // A1b and H2 overlay xb's region (xb dead after GEMM1).
    int*   counts     = (int*)d_ws;                          // 50048
    int*   offsets    = counts + 50048;                      // 50052 (+sentinel)
    int*   woff       = offsets + 50052;                     // 50048
    int*   bsums      = woff + 50048;                        // 64
    float* dinv       = (float*)(bsums + 64);                // 50048
    int*   sorted_src = (int*)(dinv + 50048);                // 800000
    float* sorted_w   = (float*)(sorted_src + 800000);       // 800000
    unsigned short* W1T = (unsigned short*)(sorted_w + 800000);       // 131072 sh (65536 w)
    unsigned short* W2T = W1T + 131072;                               // 32768 sh (16384 w)
    unsigned short* xb  = W2T + 32768;                                // 25.6M sh (12.8M w)
    unsigned short* H1  = xb + (size_t)N_NODES * IN_C;                // 12.8M sh (6.4M w)
    unsigned short* A1b = xb;                                         // overlay: 12.8M sh
    unsigned short* H2  = xb + (size_t)N_NODES * HID_C;               // overlay: 6.4M sh

    // CSR build + norm
    zero_counts_kernel<<<(N_NODES + 255) / 256, 256, 0, stream>>>(counts);
    count_kernel<<<(N_EDGES + 255) / 256, 256, 0, stream>>>(ei, counts);
    scan_part_kernel<<<SCAN_BLOCKS, 256, 0, stream>>>(counts, offsets, bsums);
    scan_sums_kernel<<<1, 64, 0, stream>>>(bsums);
    add_dinv_kernel<<<(N_NODES + 255) / 256, 256, 0, stream>>>(offsets, bsums, woff, counts, dinv);
    fill_kernel<<<(N_EDGES + 255) / 256, 256, 0, stream>>>(ei, woff, dinv, sorted_src, sorted_w);

    // bf16 casts
    cast_x_kernel<<<(N_NODES * IN_C) / 1024, 256, 0, stream>>>(x, xb);
    tcast_kernel<<<(IN_C * HID_C) / 256, 256, 0, stream>>>(W1, W1T, IN_C, HID_C);
    tcast_kernel<<<(HID_C * OUT_C) / 256, 256, 0, stream>>>(W2, W2T, HID_C, OUT_C);

    // layer 1: H1 = xb @ W1T^T  (bf16 MFMA)
    {
        dim3 grid(HID_C / 128, (N_NODES + 127) / 128);
        mfma_gemm_bt<<<grid, 256, 0, stream>>>(xb, W1T, H1, N_NODES, HID_C, IN_C);
    }
    gather_agg_kernel<HID_C, true, true><<<(N_NODES + 3) / 4, 256, 0, stream>>>(
        offsets, sorted_src, sorted_w, H1, dinv, b1, (void*)A1b);

    // layer 2: H2 = A1b @ W2T^T  (relu already applied in gather1 output)
    {
        dim3 grid(OUT_C / 128, (N_NODES + 127) / 128);
        mfma_gemm_bt<<<grid, 256, 0, stream>>>(A1b, W2T, H2, N_NODES, OUT_C, HID_C);
    }
    gather_agg_kernel<OUT_C, false, false><<<(N_NODES + 3) / 4, 256, 0, stream>>>(
        offsets, sorted_src, sorted_w, H2, dinv, b2, (void*)out);
}

// Round 5
// 428.699 us; speedup vs baseline: 3.4010x; 1.0473x over previous
//
#include <hip/hip_runtime.h>
#include <hip/hip_bf16.h>

#define N_NODES 50000
#define N_EDGES 800000
#define IN_C 512
#define HID_C 256
#define OUT_C 128
#define SCAN_BLOCKS 49  // ceil(50000 / 1024)

typedef short bf16x8 __attribute__((ext_vector_type(8)));
typedef float f32x4 __attribute__((ext_vector_type(4)));

__device__ __forceinline__ float bf2f(unsigned short u) {
    return __uint_as_float(((unsigned)u) << 16);
}
__device__ __forceinline__ unsigned short f2bf(float f) {
    __hip_bfloat16 h = __float2bfloat16(f);
    return *(unsigned short*)&h;
}

// ---------------------------------------------------------------- CSR build
__global__ void zero_counts_kernel(int* __restrict__ counts) {
    int i = blockIdx.x * blockDim.x + threadIdx.x;
    if (i < N_NODES) counts[i] = 0;
}

__global__ void count_kernel(const int* __restrict__ ei, int* __restrict__ counts) {
    int e = blockIdx.x * blockDim.x + threadIdx.x;
    if (e < N_EDGES) atomicAdd(&counts[ei[N_EDGES + e]], 1);
}

__global__ __launch_bounds__(256) void scan_part_kernel(const int* __restrict__ counts,
                                                        int* __restrict__ excl,
                                                        int* __restrict__ bsums) {
    __shared__ int tsum[256];
    const int t = threadIdx.x;
    const int base = blockIdx.x * 1024 + t * 4;
    int v[4];
    int s = 0;
#pragma unroll
    for (int j = 0; j < 4; j++) {
        int idx = base + j;
        v[j] = (idx < N_NODES) ? counts[idx] : 0;
        s += v[j];
    }
    tsum[t] = s;
    __syncthreads();
    for (int off = 1; off < 256; off <<= 1) {
        int add = (t >= off) ? tsum[t - off] : 0;
        __syncthreads();
        tsum[t] += add;
        __syncthreads();
    }
    int run = tsum[t] - s;
#pragma unroll
    for (int j = 0; j < 4; j++) {
        int idx = base + j;
        if (idx < N_NODES) excl[idx] = run;
        run += v[j];
    }
    if (t == 255) bsums[blockIdx.x] = tsum[255];
}

// wave-parallel exclusive scan of the 49 block sums (was single-threaded:
// 49 dependent global round-trips ~= 20 us; now ~2 us)
__global__ void scan_sums_kernel(int* __restrict__ bsums) {
    int ln = threadIdx.x;  // 64 threads = 1 wave
    int v = (ln < SCAN_BLOCKS) ? bsums[ln] : 0;
    for (int off = 1; off < 64; off <<= 1) {
        int u = __shfl_up(v, off, 64);
        if (ln >= off) v += u;
    }
    int excl = __shfl_up(v, 1, 64);
    if (ln == 0) excl = 0;
    if (ln < SCAN_BLOCKS) bsums[ln] = excl;
}

__global__ void add_dinv_kernel(int* __restrict__ offsets, const int* __restrict__ bsums,
                                int* __restrict__ woff, const int* __restrict__ counts,
                                float* __restrict__ dinv) {
    int i = blockIdx.x * blockDim.x + threadIdx.x;
    if (i < N_NODES) {
        int o = offsets[i] + bsums[i >> 10];
        offsets[i] = o;
        woff[i] = o;
        dinv[i] = rsqrtf(1.0f + (float)counts[i]);
    }
    if (i == 0) offsets[N_NODES] = N_EDGES;
}

__global__ void fill_kernel(const int* __restrict__ ei, int* __restrict__ woff,
                            const float* __restrict__ dinv,
                            int* __restrict__ sorted_src, float* __restrict__ sorted_w) {
    int e = blockIdx.x * blockDim.x + threadIdx.x;
    if (e < N_EDGES) {
        int s = ei[e];
        int d = ei[N_EDGES + e];
        int pos = atomicAdd(&woff[d], 1);
        sorted_src[pos] = s;
        sorted_w[pos] = dinv[s];
    }
}

// ---------------------------------------------------------------- casts
__global__ __launch_bounds__(256) void cast_x_kernel(const float* __restrict__ x,
                                                     unsigned short* __restrict__ xb) {
    size_t i = ((size_t)blockIdx.x * 256 + threadIdx.x) * 4;  // grid sized exactly
    float4 v = *(const float4*)&x[i];
    ushort4 o;
    o.x = f2bf(v.x); o.y = f2bf(v.y); o.z = f2bf(v.z); o.w = f2bf(v.w);
    *(ushort4*)&xb[i] = o;
}

// WT[n][k] = bf16(W[k][n]); grid covers N*K exactly
__global__ __launch_bounds__(256) void tcast_kernel(const float* __restrict__ W,
                                                    unsigned short* __restrict__ WT,
                                                    int K, int N) {
    int idx = blockIdx.x * 256 + threadIdx.x;
    int n = idx / K, k = idx - n * K;
    WT[idx] = f2bf(W[(size_t)k * N + n]);
}

// ---------------------------------------------------------------- MFMA GEMM
// C[M,N](bf16) = A[M,K](bf16) @ BT[N,K](bf16)^T. 128x128 block tile, BK=32,
// 256 threads = 4 waves, each wave a 64x64 quadrant via 4x4 of 16x16x32 MFMA.
__global__ __launch_bounds__(256) void mfma_gemm_bt(const unsigned short* __restrict__ A,
                                                    const unsigned short* __restrict__ BT,
                                                    unsigned short* __restrict__ C,
                                                    int M, int N, int K) {
    __shared__ unsigned short As[128 * 32];  // [row][k] 64B rows
    __shared__ unsigned short Bs[128 * 32];

    const int tid = threadIdx.x;
    const int w = tid >> 6;
    const int ln = tid & 63;
    const int br = blockIdx.y * 128;
    const int bc = blockIdx.x * 128;

    const int quad = ln >> 4;
    const int l16 = ln & 15;
    const int wr = (w >> 1) * 64;
    const int wc = (w & 1) * 64;

    const int crow = ln >> 2;
    const int koff = (ln & 3) * 8;

    f32x4 acc[4][4];
#pragma unroll
    for (int mt = 0; mt < 4; mt++)
#pragma unroll
        for (int nt = 0; nt < 4; nt++) acc[mt][nt] = (f32x4){0.f, 0.f, 0.f, 0.f};

    for (int kk = 0; kk < K; kk += 32) {
#pragma unroll
        for (int t = 0; t < 2; t++) {
            int c = w + t * 4;
            int row = br + c * 16 + crow;
            row = row < M ? row : M - 1;  // clamp (dup read, stores guarded)
            const unsigned short* gp = A + (size_t)row * K + kk + koff;
            unsigned short* lp = As + c * 512 + ln * 8;
            __builtin_amdgcn_global_load_lds((const __attribute__((address_space(1))) void*)gp,
                                             (__attribute__((address_space(3))) void*)lp,
                                             16, 0, 0);
        }
#pragma unroll
        for (int t = 0; t < 2; t++) {
            int c = w + t * 4;
            int row = bc + c * 16 + crow;
            const unsigned short* gp = BT + (size_t)row * K + kk + koff;
            unsigned short* lp = Bs + c * 512 + ln * 8;
            __builtin_amdgcn_global_load_lds((const __attribute__((address_space(1))) void*)gp,
                                             (__attribute__((address_space(3))) void*)lp,
                                             16, 0, 0);
        }
        __syncthreads();

        bf16x8 af[4], bfr[4];
#pragma unroll
        for (int mt = 0; mt < 4; mt++)
            af[mt] = *(const bf16x8*)&As[(wr + mt * 16 + l16) * 32 + quad * 8];
#pragma unroll
        for (int nt = 0; nt < 4; nt++)
            bfr[nt] = *(const bf16x8*)&Bs[(wc + nt * 16 + l16) * 32 + quad * 8];
#pragma unroll
        for (int mt = 0; mt < 4; mt++)
#pragma unroll
            for (int nt = 0; nt < 4; nt++)
                acc[mt][nt] = __builtin_amdgcn_mfma_f32_16x16x32_bf16(af[mt], bfr[nt],
                                                                      acc[mt][nt], 0, 0, 0);
        __syncthreads();
    }

#pragma unroll
    for (int mt = 0; mt < 4; mt++) {
#pragma unroll
        for (int r = 0; r < 4; r++) {
            int gr = br + wr + mt * 16 + quad * 4 + r;
            if (gr < M) {
#pragma unroll
                for (int nt = 0; nt < 4; nt++) {
                    int gc = bc + wc + nt * 16 + l16;
                    C[(size_t)gr * N + gc] = f2bf(acc[mt][nt][r]);
                }
            }
        }
    }
}

// ------------------------------------------------------- gather aggregation
// One wave per node. Wave splits into NG = 64/(C/8) groups; each group owns
// an edge substream (stride NG) and loads full rows as 16B bf16x8 per lane.
// Partial sums combined across groups with shfl_xor; group 0 writes.
// out[i,:] = relu?( dinv[i]^2*H[i,:] + b + sum_e dinv[i]*sw[e]*H[src,:] )
template <int C, bool RELU, bool BF16_OUT>
__global__ __launch_bounds__(256) void gather_agg_kernel(const int* __restrict__ offsets,
                                                         const int* __restrict__ ssrc,
                                                         const float* __restrict__ sw,
                                                         const unsigned short* __restrict__ H,
                                                         const float* __restrict__ dinv,
                                                         const float* __restrict__ bias,
                                                         void* __restrict__ outv) {
    constexpr int G = C / 8;    // lanes per group: 32 (C=256), 16 (C=128)
    constexpr int NG = 64 / G;  // groups per wave: 2, 4
    const int node = blockIdx.x * 4 + (threadIdx.x >> 6);
    if (node >= N_NODES) return;
    const int ln = threadIdx.x & 63;
    const int g = ln / G;
    const int l = ln % G;
    const int c0 = l * 8;
    const float di = dinv[node];

    float acc[8] = {};
    if (g == 0) {  // self term + bias exactly once
        bf16x8 h = *(const bf16x8*)&H[(size_t)node * C + c0];
#pragma unroll
        for (int j = 0; j < 8; j++)
            acc[j] = di * di * bf2f((unsigned short)h[j]) + bias[c0 + j];
    }

    int k = offsets[node] + g;
    const int k1 = offsets[node + 1];
    // 2-edge unroll per group: up to 2*NG row loads in flight per wave
    for (; k + NG < k1; k += 2 * NG) {
        int s0 = ssrc[k], s1 = ssrc[k + NG];
        float w0 = di * sw[k], w1 = di * sw[k + NG];
        bf16x8 h0 = *(const bf16x8*)&H[(size_t)s0 * C + c0];
        bf16x8 h1 = *(const bf16x8*)&H[(size_t)s1 * C + c0];
#pragma unroll
        for (int j = 0; j < 8; j++)
            acc[j] += w0 * bf2f((unsigned short)h0[j]) + w1 * bf2f((unsigned short)h1[j]);
    }
    if (k < k1) {
        int s0 = ssrc[k];
        float w0 = di * sw[k];
        bf16x8 h0 = *(const bf16x8*)&H[(size_t)s0 * C + c0];
#pragma unroll
        for (int j = 0; j < 8; j++) acc[j] += w0 * bf2f((unsigned short)h0[j]);
    }

    // combine group partials (every lane ends with the full sum)
#pragma unroll
    for (int m = G; m < 64; m <<= 1) {
#pragma unroll
        for (int j = 0; j < 8; j++) acc[j] += __shfl_xor(acc[j], m, 64);
    }

    if (g == 0) {
        if (RELU) {
#pragma unroll
            for (int j = 0; j < 8; j++) acc[j] = fmaxf(acc[j], 0.0f);
        }
        if (BF16_OUT) {
            bf16x8 o;
#pragma unroll
            for (int j = 0; j < 8; j++) o[j] = (short)f2bf(acc[j]);
            *(bf16x8*)&((unsigned short*)outv)[(size_t)node * C + c0] = o;
        } else {
            float* out = (float*)outv;
            *(float4*)&out[(size_t)node * C + c0] = make_float4(acc[0], acc[1], acc[2], acc[3]);
            *(float4*)&out[(size_t)node * C + c0 + 4] = make_float4(acc[4], acc[5], acc[6], acc[7]);
        }
    }
}

// ---------------------------------------------------------------- launcher
extern "C" void kernel_launch(void* const* d_in, const int* in_sizes, int n_in,
                              void* d_out, int out_size, void* d_ws, size_t ws_size,
                              hipStream_t stream) {
    const float* x  = (const float*)d_in[0];
    const int*   ei = (const int*)d_in[1];
    const float* W1 = (const float*)d_in[2];
    const float* b1 = (const float*)d_in[3];
    const float* W2 = (const float*)d_in[4];
    const float* b2 = (const float*)d_in[5];
    float* out = (float*)d_out;

    // workspace layout (4-byte words). Total 21,082,180 words = 84.3 MiB
    // (< known-good 98 MiB; R2's 101.5 MiB overflowed and corrupted inputs).
    int*   counts     = (int*)d_ws;                          // 50048
    int*   offsets    = counts + 50048;                      // 50052 (+sentinel)
    int*   woff       = offsets + 50052;                     // 50048
    int*   bsums      = woff + 50048;                        // 64
    float* dinv       = (float*)(bsums + 64);                // 50048
    int*   sorted_src = (int*)(dinv + 50048);                // 800000
    float* sorted_w   = (float*)(sorted_src + 800000);       // 800000
    unsigned short* W1T = (unsigned short*)(sorted_w + 800000);       // 131072 sh
    unsigned short* W2T = W1T + 131072;                               // 32768 sh
    unsigned short* xb  = W2T + 32768;                                // 25.6M sh
    unsigned short* H1  = xb + (size_t)N_NODES * IN_C;                // 12.8M sh
    unsigned short* A1b = xb;                                         // overlay
    unsigned short* H2  = xb + (size_t)N_NODES * HID_C;               // overlay

    // CSR build + norm
    zero_counts_kernel<<<(N_NODES + 255) / 256, 256, 0, stream>>>(counts);
    count_kernel<<<(N_EDGES + 255) / 256, 256, 0, stream>>>(ei, counts);
    scan_part_kernel<<<SCAN_BLOCKS, 256, 0, stream>>>(counts, offsets, bsums);
    scan_sums_kernel<<<1, 64, 0, stream>>>(bsums);
    add_dinv_kernel<<<(N_NODES + 255) / 256, 256, 0, stream>>>(offsets, bsums, woff, counts, dinv);
    fill_kernel<<<(N_EDGES + 255) / 256, 256, 0, stream>>>(ei, woff, dinv, sorted_src, sorted_w);

    // bf16 casts
    cast_x_kernel<<<(N_NODES * IN_C) / 1024, 256, 0, stream>>>(x, xb);
    tcast_kernel<<<(IN_C * HID_C) / 256, 256, 0, stream>>>(W1, W1T, IN_C, HID_C);
    tcast_kernel<<<(HID_C * OUT_C) / 256, 256, 0, stream>>>(W2, W2T, HID_C, OUT_C);

    // layer 1: H1 = xb @ W1T^T  (bf16 MFMA)
    {
        dim3 grid(HID_C / 128, (N_NODES + 127) / 128);
        mfma_gemm_bt<<<grid, 256, 0, stream>>>(xb, W1T, H1, N_NODES, HID_C, IN_C);
    }
    gather_agg_kernel<HID_C, true, true><<<(N_NODES + 3) / 4, 256, 0, stream>>>(
        offsets, sorted_src, sorted_w, H1, dinv, b1, (void*)A1b);

    // layer 2: H2 = A1b @ W2T^T  (relu already applied in gather1 output)
    {
        dim3 grid(OUT_C / 128, (N_NODES + 127) / 128);
        mfma_gemm_bt<<<grid, 256, 0, stream>>>(A1b, W2T, H2, N_NODES, OUT_C, HID_C);
    }
    gather_agg_kernel<OUT_C, false, false><<<(N_NODES + 3) / 4, 256, 0, stream>>>(
        offsets, sorted_src, sorted_w, H2, dinv, b2, (void*)out);
}